// Round 3
// baseline (65.748 us; speedup 1.0000x reference)
//
#include <hip/hip_runtime.h>

// Problem constants
#define BB 32
#define KK 5
#define TT 20
#define VV 9488
#define HH 1024
#define NSPLIT 16
#define CHUNK (VV / NSPLIT)   // 593 exactly

// Output layout (floats), concatenated in return order:
// out0 beam_seq          : [0,        3360)
// out1 beam_seq_logprobs : [3360,     31883040)
// out2 beam_logprobs_sum : [31883040, 31883200)
// out3 new_state         : [31883200, 32210880)
#define OFF1 3360
#define OFF2 31883040
#define OFF3 31883200

typedef float f4 __attribute__((ext_vector_type(4)));

__device__ __forceinline__ bool better(float av, int ai, float bv, int bi) {
    // total order: value descending, then index ascending (jax top_k tie-break)
    return (av > bv) || (av == bv && ai < bi);
}

// Branch-free descending insert of (val,idx) into sorted 5-list. Static indices only.
__device__ __forceinline__ void insert5(float tv[5], int ti[5], float val, int idx) {
#pragma unroll
    for (int j = 4; j >= 1; --j) {
        bool bj  = better(val, idx, tv[j],   ti[j]);
        bool bj1 = better(val, idx, tv[j-1], ti[j-1]);
        float nv = bj ? (bj1 ? tv[j-1] : val) : tv[j];
        int   ni = bj ? (bj1 ? ti[j-1] : idx) : ti[j];
        tv[j] = nv; ti[j] = ni;
    }
    bool b0 = better(val, idx, tv[0], ti[0]);
    ti[0] = b0 ? idx : ti[0];
    tv[0] = b0 ? val : tv[0];
}

// Merge two descending sorted 5-lists, keep top-5. Static indices only:
// merged[n] = worst over {i+j==n} of best(A[i], B[j]).
__device__ __forceinline__ void merge_sorted5(float av[5], int ai[5],
                                              const float bv[5], const int bi[5]) {
    float ov[5]; int oi[5];
#pragma unroll
    for (int n = 0; n < 5; ++n) {
        float mv = 0.f; int mi = 0;
#pragma unroll
        for (int i = 0; i <= n; ++i) {
            const int j = n - i;
            float cv; int ci;
            if (better(av[i], ai[i], bv[j], bi[j])) { cv = av[i]; ci = ai[i]; }
            else                                    { cv = bv[j]; ci = bi[j]; }
            if (i == 0 || better(mv, mi, cv, ci)) { mv = cv; mi = ci; }  // keep worst
        }
        ov[n] = mv; oi[n] = mi;
    }
#pragma unroll
    for (int n = 0; n < 5; ++n) { av[n] = ov[n]; ai[n] = oi[n]; }
}

// Shuffle-allreduce merge: after log2 rounds, ALL lanes hold the merged top-5.
template<int MAXST>
__device__ __forceinline__ void wave_merge(float tv[5], int ti[5]) {
#pragma unroll
    for (int st = 1; st <= MAXST; st <<= 1) {
        float bv[5]; int bi[5];
#pragma unroll
        for (int j = 0; j < 5; ++j) {
            bv[j] = __shfl_xor(tv[j], st);
            bi[j] = __shfl_xor(ti[j], st);
        }
        merge_sorted5(tv, ti, bv, bi);
    }
}

// Phase 1: 512 blocks; block (b, part) scans CHUNK v-values over all 5 beams.
__global__ __launch_bounds__(256) void topk_part_kernel(
    const float* __restrict__ logprobs,      // (B*K, V)
    const float* __restrict__ sums,          // (B, K)
    float* __restrict__ pv,                  // (B*NSPLIT, 5)
    int*   __restrict__ pi)
{
    const int b    = blockIdx.x / NSPLIT;
    const int part = blockIdx.x % NSPLIT;
    const int tid  = threadIdx.x;
    const int v0   = part * CHUNK;

    float tv[5]; int ti[5];
#pragma unroll
    for (int j = 0; j < 5; ++j) { tv[j] = -INFINITY; ti[j] = 0x7FFFFF00 + j; }

#pragma unroll
    for (int k = 0; k < KK; ++k) {
        const float s = sums[b * KK + k];
        const float* lp = logprobs + (size_t)(b * KK + k) * VV;
        for (int v = v0 + tid; v < v0 + CHUNK; v += 256)
            insert5(tv, ti, s + lp[v], k * VV + v);
    }

    wave_merge<32>(tv, ti);   // all 64 lanes now hold the wave's top-5

    __shared__ float lv[4][5];
    __shared__ int   li[4][5];
    const int wid = tid >> 6, lane = tid & 63;
    if (lane == 0) {
#pragma unroll
        for (int j = 0; j < 5; ++j) { lv[wid][j] = tv[j]; li[wid][j] = ti[j]; }
    }
    __syncthreads();
    if (tid < 64) {
        if (tid < 4) {
#pragma unroll
            for (int j = 0; j < 5; ++j) { tv[j] = lv[tid][j]; ti[j] = li[tid][j]; }
        } else {
#pragma unroll
            for (int j = 0; j < 5; ++j) { tv[j] = -INFINITY; ti[j] = 0x7FFFFF00 + j; }
        }
        wave_merge<2>(tv, ti);
        if (tid == 0) {
#pragma unroll
            for (int j = 0; j < 5; ++j) {
                pv[(size_t)blockIdx.x * 5 + j] = tv[j];
                pi[(size_t)blockIdx.x * 5 + j] = ti[j];
            }
        }
    }
}

// Phase 2: 3712 blocks. Every wave inline-merges its batch's 16 partial lists
// (no extra kernel), then does its copy/write role.
__global__ __launch_bounds__(256) void scatter_kernel(
    const float* __restrict__ logprobs,      // (B*K, V)
    const int*   __restrict__ beam_seq_in,   // (B, K, T)
    const float* __restrict__ bslp_in,       // (B, K, T, V)
    const float* __restrict__ state_in,      // (2, B*K, H)
    const float* __restrict__ pv,
    const int*   __restrict__ pi,
    float* __restrict__ out)
{
    const int bid  = blockIdx.x;
    const int tid  = threadIdx.x;
    const int lane = tid & 63;

    int b, k = 0, t = 0, role, r = 0;
    if (bid < 3360)      { role = 0; b = bid / 105; int rem = bid % 105; k = rem / 21; t = rem % 21; }
    else if (bid < 3680) { role = 1; r = bid - 3360; int i = r % 160; b = i / 5; k = i % 5; }
    else                 { role = 2; b = bid - 3680; }

    // per-wave merge of the 16 sorted-5 partial lists for batch b
    float tv[5]; int ti[5];
    if (lane < NSPLIT) {
        const size_t base = ((size_t)b * NSPLIT + lane) * 5;
#pragma unroll
        for (int j = 0; j < 5; ++j) { tv[j] = pv[base + j]; ti[j] = pi[base + j]; }
    } else {
#pragma unroll
        for (int j = 0; j < 5; ++j) { tv[j] = -INFINITY; ti[j] = 0x7FFFFF00 + j; }
    }
    wave_merge<32>(tv, ti);   // all lanes now hold final top-5 for batch b

    if (role == 0) {
        // one 9488-float row of beam_seq_logprobs output; k is block-uniform
        int sidx = 0;
#pragma unroll
        for (int j = 0; j < 5; ++j) if (k == j) sidx = ti[j];   // static reg indices
        const int beam = sidx / VV;
        const float* src = (t < TT)
            ? bslp_in  + ((size_t)((b * KK + beam) * TT + t)) * VV
            : logprobs + (size_t)(b * KK + beam) * VV;
        const f4* s4 = (const f4*)src;
        f4* d4 = (f4*)(out + OFF1 + (size_t)bid * VV);
        for (int i = tid; i < VV / 4; i += 256) {
            f4 v = s4[i];
            __builtin_nontemporal_store(v, &d4[i]);
        }
    } else if (role == 1) {
        // one 1024-float row of new_state
        const int s = r / 160;
        int sidx = 0;
#pragma unroll
        for (int j = 0; j < 5; ++j) if (k == j) sidx = ti[j];
        const int beam = sidx / VV;
        const f4* s4 = (const f4*)(state_in + ((size_t)s * (BB * KK) + b * KK + beam) * HH);
        f4* d4 = (f4*)(out + OFF3 + (size_t)r * HH);
        for (int j = tid; j < HH / 4; j += 256) {
            f4 v = s4[j];
            __builtin_nontemporal_store(v, &d4[j]);
        }
    } else {
        // small outputs for batch b: beam_seq (as float) + beam_logprobs_sum
        if (tid < 105) {
            const int k2 = tid / 21, t2 = tid % 21;
            int sidx = 0;
#pragma unroll
            for (int j = 0; j < 5; ++j) if (k2 == j) sidx = ti[j];
            const int beam = sidx / VV;
            const int sel  = sidx - beam * VV;
            const int val  = (t2 < TT) ? beam_seq_in[(size_t)(b * KK + beam) * TT + t2] : sel;
            out[(size_t)b * 105 + tid] = (float)val;
        }
#pragma unroll
        for (int j = 0; j < 5; ++j)
            if (tid == 105 + j) out[OFF2 + b * KK + j] = tv[j];
    }
}

extern "C" void kernel_launch(void* const* d_in, const int* in_sizes, int n_in,
                              void* d_out, int out_size, void* d_ws, size_t ws_size,
                              hipStream_t stream) {
    const float* logprobs = (const float*)d_in[0];
    const int*   beam_seq = (const int*)  d_in[1];
    const float* bslp     = (const float*)d_in[2];
    const float* sums     = (const float*)d_in[3];
    const float* state    = (const float*)d_in[4];

    float* pv = (float*)d_ws;
    int*   pi = (int*)(pv + BB * NSPLIT * 5);
    float* out = (float*)d_out;

    topk_part_kernel<<<BB * NSPLIT, 256, 0, stream>>>(logprobs, sums, pv, pi);

    const int nblocks = 3360 + 320 + 32;   // bslp rows + state rows + small-out blocks
    scatter_kernel<<<nblocks, 256, 0, stream>>>(logprobs, beam_seq, bslp, state,
                                                pv, pi, out);
}

// Round 4
// 65.406 us; speedup vs baseline: 1.0052x; 1.0052x over previous
//
#include <hip/hip_runtime.h>

// Problem constants
#define BB 32
#define KK 5
#define TT 20
#define VV 9488
#define HH 1024
#define NSPLIT 16
#define CHUNK (VV / NSPLIT)   // 593 exactly

// Output layout (floats), concatenated in return order:
// out0 beam_seq          : [0,        3360)
// out1 beam_seq_logprobs : [3360,     31883040)
// out2 beam_logprobs_sum : [31883040, 31883200)
// out3 new_state         : [31883200, 32210880)
#define OFF1 3360
#define OFF2 31883040
#define OFF3 31883200

typedef float f4 __attribute__((ext_vector_type(4)));

__device__ __forceinline__ bool better(float av, int ai, float bv, int bi) {
    // total order: value descending, then index ascending (jax top_k tie-break)
    return (av > bv) || (av == bv && ai < bi);
}

// Branch-free descending insert of (val,idx) into sorted 5-list. Static indices only.
__device__ __forceinline__ void insert5(float tv[5], int ti[5], float val, int idx) {
#pragma unroll
    for (int j = 4; j >= 1; --j) {
        bool bj  = better(val, idx, tv[j],   ti[j]);
        bool bj1 = better(val, idx, tv[j-1], ti[j-1]);
        float nv = bj ? (bj1 ? tv[j-1] : val) : tv[j];
        int   ni = bj ? (bj1 ? ti[j-1] : idx) : ti[j];
        tv[j] = nv; ti[j] = ni;
    }
    bool b0 = better(val, idx, tv[0], ti[0]);
    ti[0] = b0 ? idx : ti[0];
    tv[0] = b0 ? val : tv[0];
}

// Merge two descending sorted 5-lists, keep top-5. Static indices only:
// merged[n] = worst over {i+j==n} of best(A[i], B[j]).
__device__ __forceinline__ void merge_sorted5(float av[5], int ai[5],
                                              const float bv[5], const int bi[5]) {
    float ov[5]; int oi[5];
#pragma unroll
    for (int n = 0; n < 5; ++n) {
        float mv = 0.f; int mi = 0;
#pragma unroll
        for (int i = 0; i <= n; ++i) {
            const int j = n - i;
            float cv; int ci;
            if (better(av[i], ai[i], bv[j], bi[j])) { cv = av[i]; ci = ai[i]; }
            else                                    { cv = bv[j]; ci = bi[j]; }
            if (i == 0 || better(mv, mi, cv, ci)) { mv = cv; mi = ci; }  // keep worst
        }
        ov[n] = mv; oi[n] = mi;
    }
#pragma unroll
    for (int n = 0; n < 5; ++n) { av[n] = ov[n]; ai[n] = oi[n]; }
}

// Shuffle-allreduce merge across lanes: after log2 rounds all lanes in each
// 2*MAXST-lane group hold the group's merged top-5.
template<int MAXST>
__device__ __forceinline__ void wave_merge(float tv[5], int ti[5]) {
#pragma unroll
    for (int st = 1; st <= MAXST; st <<= 1) {
        float bv[5]; int bi[5];
#pragma unroll
        for (int j = 0; j < 5; ++j) {
            bv[j] = __shfl_xor(tv[j], st);
            bi[j] = __shfl_xor(ti[j], st);
        }
        merge_sorted5(tv, ti, bv, bi);
    }
}

// Phase 1: 512 blocks; block (b, part) scans CHUNK v-values over all 5 beams.
__global__ __launch_bounds__(256) void topk_part_kernel(
    const float* __restrict__ logprobs,      // (B*K, V)
    const float* __restrict__ sums,          // (B, K)
    float* __restrict__ pv,                  // (B*NSPLIT, 5)
    int*   __restrict__ pi)
{
    const int b    = blockIdx.x / NSPLIT;
    const int part = blockIdx.x % NSPLIT;
    const int tid  = threadIdx.x;
    const int v0   = part * CHUNK;

    float tv[5]; int ti[5];
#pragma unroll
    for (int j = 0; j < 5; ++j) { tv[j] = -INFINITY; ti[j] = 0x7FFFFF00 + j; }

#pragma unroll
    for (int k = 0; k < KK; ++k) {
        const float s = sums[b * KK + k];
        const float* lp = logprobs + (size_t)(b * KK + k) * VV;
        for (int v = v0 + tid; v < v0 + CHUNK; v += 256)
            insert5(tv, ti, s + lp[v], k * VV + v);
    }

    wave_merge<32>(tv, ti);   // all 64 lanes now hold the wave's top-5

    __shared__ float lv[4][5];
    __shared__ int   li[4][5];
    const int wid = tid >> 6, lane = tid & 63;
    if (lane == 0) {
#pragma unroll
        for (int j = 0; j < 5; ++j) { lv[wid][j] = tv[j]; li[wid][j] = ti[j]; }
    }
    __syncthreads();
    if (tid < 64) {
        if (tid < 4) {
#pragma unroll
            for (int j = 0; j < 5; ++j) { tv[j] = lv[tid][j]; ti[j] = li[tid][j]; }
        } else {
#pragma unroll
            for (int j = 0; j < 5; ++j) { tv[j] = -INFINITY; ti[j] = 0x7FFFFF00 + j; }
        }
        wave_merge<2>(tv, ti);
        if (tid == 0) {
#pragma unroll
            for (int j = 0; j < 5; ++j) {
                pv[(size_t)blockIdx.x * 5 + j] = tv[j];
                pi[(size_t)blockIdx.x * 5 + j] = ti[j];
            }
        }
    }
}

// Phase 2: 32 blocks x 64; pure-shuffle merge of 16 sorted-5 lists per batch.
__global__ __launch_bounds__(64) void topk_merge_kernel(
    const float* __restrict__ pv,
    const int*   __restrict__ pi,
    int*   __restrict__ ws_beam,
    int*   __restrict__ ws_sel,
    float* __restrict__ ws_sum)
{
    const int b   = blockIdx.x;
    const int tid = threadIdx.x;

    float tv[5]; int ti[5];
    if (tid < NSPLIT) {
        const size_t base = ((size_t)b * NSPLIT + tid) * 5;
#pragma unroll
        for (int j = 0; j < 5; ++j) { tv[j] = pv[base + j]; ti[j] = pi[base + j]; }
    } else {
#pragma unroll
        for (int j = 0; j < 5; ++j) { tv[j] = -INFINITY; ti[j] = 0x7FFFFF00 + j; }
    }

    wave_merge<8>(tv, ti);    // lanes 0..15 merged -> lanes 0..15 all hold final

    if (tid == 0) {
#pragma unroll
        for (int j = 0; j < 5; ++j) {
            const int idx  = ti[j];
            const int beam = idx / VV;
            ws_beam[b * KK + j] = beam;
            ws_sel [b * KK + j] = idx - beam * VV;
            ws_sum [b * KK + j] = tv[j];
        }
    }
}

// Phase 3: copy/scatter. Reads tiny precomputed ws_* (L2-hot), plain stores.
__global__ __launch_bounds__(256) void scatter_kernel(
    const float* __restrict__ logprobs,      // (B*K, V)
    const int*   __restrict__ beam_seq_in,   // (B, K, T)
    const float* __restrict__ bslp_in,       // (B, K, T, V)
    const float* __restrict__ state_in,      // (2, B*K, H)
    const int*   __restrict__ ws_beam,
    const int*   __restrict__ ws_sel,
    const float* __restrict__ ws_sum,
    float* __restrict__ out)
{
    const int bid = blockIdx.x;
    const int tid = threadIdx.x;
    const int NROWS = BB * KK * (TT + 1);    // 3360

    if (bid < NROWS) {
        // one 9488-float row of beam_seq_logprobs output
        const int b   = bid / (KK * (TT + 1));
        const int rem = bid % (KK * (TT + 1));
        const int k   = rem / (TT + 1);
        const int t   = rem % (TT + 1);
        const int beam = ws_beam[b * KK + k];
        const float* src = (t < TT)
            ? bslp_in  + ((size_t)((b * KK + beam) * TT + t)) * VV
            : logprobs + (size_t)(b * KK + beam) * VV;
        const f4* s4 = (const f4*)src;
        f4* d4 = (f4*)(out + OFF1 + (size_t)bid * VV);
        for (int i = tid; i < VV / 4; i += 256) d4[i] = s4[i];
    } else if (bid < NROWS + 2 * BB * KK) {
        // one 1024-float row of new_state
        const int r = bid - NROWS;
        const int s = r / (BB * KK);
        const int i = r % (BB * KK);
        const int b = i / KK;
        const int beam = ws_beam[i];
        const f4* s4 = (const f4*)(state_in + ((size_t)s * (BB * KK) + b * KK + beam) * HH);
        f4* d4 = (f4*)(out + OFF3 + (size_t)r * HH);
        for (int j = tid; j < HH / 4; j += 256) d4[j] = s4[j];
    } else {
        // small outputs: beam_seq (as float) and beam_logprobs_sum
        for (int j = tid; j < NROWS; j += 256) {
            const int b   = j / (KK * (TT + 1));
            const int rem = j % (KK * (TT + 1));
            const int k   = rem / (TT + 1);
            const int t   = rem % (TT + 1);
            const int bk  = b * KK + k;
            int val;
            if (t < TT) val = beam_seq_in[(size_t)(b * KK + ws_beam[bk]) * TT + t];
            else        val = ws_sel[bk];
            out[j] = (float)val;
        }
        for (int j = tid; j < BB * KK; j += 256) out[OFF2 + j] = ws_sum[j];
    }
}

extern "C" void kernel_launch(void* const* d_in, const int* in_sizes, int n_in,
                              void* d_out, int out_size, void* d_ws, size_t ws_size,
                              hipStream_t stream) {
    const float* logprobs = (const float*)d_in[0];
    const int*   beam_seq = (const int*)  d_in[1];
    const float* bslp     = (const float*)d_in[2];
    const float* sums     = (const float*)d_in[3];
    const float* state    = (const float*)d_in[4];

    float* pv      = (float*)d_ws;
    int*   pi      = (int*)(pv + BB * NSPLIT * 5);
    int*   ws_beam = pi + BB * NSPLIT * 5;
    int*   ws_sel  = ws_beam + BB * KK;
    float* ws_sum  = (float*)(ws_sel + BB * KK);
    float* out     = (float*)d_out;

    topk_part_kernel<<<BB * NSPLIT, 256, 0, stream>>>(logprobs, sums, pv, pi);
    topk_merge_kernel<<<BB, 64, 0, stream>>>(pv, pi, ws_beam, ws_sel, ws_sum);

    const int nblocks = 3360 + 320 + 1;   // bslp rows + state rows + small-out block
    scatter_kernel<<<nblocks, 256, 0, stream>>>(logprobs, beam_seq, bslp, state,
                                                ws_beam, ws_sel, ws_sum, out);
}